// Round 8
// baseline (36.561 us; speedup 1.0000x reference)
//
#include <hip/hip_runtime.h>

// DAA autoencoder: two masked-reduction layers.
//   layer0: h[b][o]   = min_i ( sel0[o][i] ? x[b][i] : 2.0f )   (t-norm)
//   layer1: out[b][o] = max_i ( sel1[o][i] ? h[b][i] : -1.0f )  (t-conorm)
// B=256, IN=1024, HID=512.
//
// R7 lesson: the binding pipe is the UNIFORM addend fetch: 1 ds_read_b128
// (~12 cyc, single LDS pipe/CU) per 4 edges-per-lane vs only 12 CU-cyc of
// VALU -> LDS pipe 4x oversubscribed (~10 us/layer). R8: batch-tile V=2 —
// each lane accumulates 2 batches (b, b+64), halving uniform fetches per
// edge (acc[2][2]; per k-step: 2 ds_read + 2 global x + 24 VALU = 16 edges
// /lane). sel->addend expansion folded into LDS staging (int4 cndmask),
// removing the a0/a1 ws arrays; pack kernel is transpose-only.
//
// Bit-exactness: addend = sel ? 0.0f : +/-inf; x + 0 == x exactly; +/-inf
// never wins min/max vs finite; acc init = off (2.0/-1.0) reproduces the
// all-deselected row exactly.

#define NB 256   // batch

// ---- transpose x[256][1024] -> xT4[256][256] (float4 over i) -------------
__global__ __launch_bounds__(256) void pack_x(
    const float* __restrict__ in, float4* __restrict__ outT4)
{
    __shared__ float t[64][65];                 // [b][i] tile, +1 pad
    const int bx = blockIdx.x % 16;             // i-tile (1024/64)
    const int by = blockIdx.x / 16;             // b-tile (256/64)
    const int i0 = bx * 64, b0 = by * 64;

    const int li = threadIdx.x & 63;
    const int lb = threadIdx.x >> 6;
#pragma unroll
    for (int r = 0; r < 64; r += 4)
        t[lb + r][li] = in[(size_t)(b0 + lb + r) * 1024 + i0 + li];
    __syncthreads();

    const int sb = threadIdx.x & 63;
    const int si = threadIdx.x >> 6;
#pragma unroll
    for (int p = 0; p < 16; p += 4) {
        const int i4 = si + p;
        float4 v = make_float4(t[sb][4 * i4 + 0], t[sb][4 * i4 + 1],
                               t[sb][4 * i4 + 2], t[sb][4 * i4 + 3]);
        outT4[(size_t)(i0 / 4 + i4) * NB + b0 + sb] = v;
    }
}

// ---- masked min/max layer, OT=2 outputs x V=2 batch-chunks per lane ------
template<int INF, int S, bool ISMIN, bool TOUT>
__global__ __launch_bounds__(64 * S, 8) void daa_layer(
    const float4* __restrict__ inT4,    // [INF/4][NB]
    const int* __restrict__ sel,        // [OUTF][INF] 0/1
    float* __restrict__ out, int OUTF)
{
    constexpr int C4  = INF / 4 / S;    // float4 k-steps per wave group
    constexpr int NI4 = 2 * INF / 4;    // int4 count for the 2 sel rows
    const int tid  = threadIdx.x;
    const int lane = tid & 63;
    const int s    = __builtin_amdgcn_readfirstlane(tid >> 6);
    const int bch  = blockIdx.x & 1;    // which 128-batch half
    const int o0   = (blockIdx.x >> 1) * 2;
    const int bA   = bch * 128 + lane;  // lane's first batch; second = bA+64
    const float off = ISMIN ? 2.0f : -1.0f;
    const float inf = ISMIN ? __builtin_inff() : -__builtin_inff();

    // ---- stage sel rows o0, o0+1 expanded to float addends in LDS --------
    __shared__ float4 aLDS[NI4];
    if (tid < NI4) {
        const int4 v = ((const int4*)(sel + (size_t)o0 * INF))[tid];
        aLDS[tid] = make_float4(v.x ? 0.f : inf, v.y ? 0.f : inf,
                                v.z ? 0.f : inf, v.w ? 0.f : inf);
    }
    __syncthreads();

    float acc[2][2];                    // [u: output row][v: batch chunk]
    acc[0][0] = acc[0][1] = acc[1][0] = acc[1][1] = off;

    const float4* __restrict__ xp  = inT4 + (size_t)(s * C4) * NB + bA;
    const float4* __restrict__ a0p = aLDS + s * C4;
    const float4* __restrict__ a1p = aLDS + INF / 4 + s * C4;

#define MM(A, X, AV)                                                   \
    do {                                                               \
        if (ISMIN) {                                                   \
            A = fminf(fminf(A, (X).x + (AV).x), (X).y + (AV).y);       \
            A = fminf(fminf(A, (X).z + (AV).z), (X).w + (AV).w);       \
        } else {                                                       \
            A = fmaxf(fmaxf(A, (X).x + (AV).x), (X).y + (AV).y);       \
            A = fmaxf(fmaxf(A, (X).z + (AV).z), (X).w + (AV).w);       \
        }                                                              \
    } while (0)

    // 2-deep x prefetch; addend reads pipelined by lgkmcnt.
    float4 x0 = xp[0], x1 = xp[64];
    for (int c = 0; c < C4; ++c) {
        float4 nx0, nx1;
        if (c + 1 < C4) {
            nx0 = xp[(size_t)(c + 1) * NB];
            nx1 = xp[(size_t)(c + 1) * NB + 64];
        }
        const float4 a0v = a0p[c];      // wave-uniform ds_read_b128
        const float4 a1v = a1p[c];
        MM(acc[0][0], x0, a0v); MM(acc[0][1], x1, a0v);
        MM(acc[1][0], x0, a1v); MM(acc[1][1], x1, a1v);
        x0 = nx0; x1 = nx1;
    }
#undef MM

    // ---- combine the S wave partials per (b,o) through LDS ---------------
    __shared__ float red[S][2][2][64];  // [s][u][v][lane]
#pragma unroll
    for (int u = 0; u < 2; ++u)
#pragma unroll
        for (int v = 0; v < 2; ++v) red[s][u][v][lane] = acc[u][v];
    __syncthreads();

    if (tid < 128) {
        const int v  = tid >> 6;
        const int ln = tid & 63;
        const int b  = bch * 128 + v * 64 + ln;
        float r[2];
#pragma unroll
        for (int u = 0; u < 2; ++u) {
            float q = red[0][u][v][ln];
#pragma unroll
            for (int ss = 1; ss < S; ++ss) {
                const float w = red[ss][u][v][ln];
                q = ISMIN ? fminf(q, w) : fmaxf(q, w);
            }
            r[u] = q;
        }
        const float2 r2 = make_float2(r[0], r[1]);
        if (TOUT)   // transposed h layout: element (o,b) at ((o>>2)*NB+b)*4+(o&3)
            *(float2*)(out + ((size_t)(o0 >> 2) * NB + b) * 4 + (o0 & 3)) = r2;
        else        // out[b][o0..o0+1]
            *(float2*)(out + (size_t)b * OUTF + o0) = r2;
    }
}

extern "C" void kernel_launch(void* const* d_in, const int* in_sizes, int n_in,
                              void* d_out, int out_size, void* d_ws, size_t ws_size,
                              hipStream_t stream) {
    const float* x    = (const float*)d_in[0];  // [256,1024] f32
    const int*   sel0 = (const int*)d_in[1];    // [512,1024] i32
    const int*   sel1 = (const int*)d_in[2];    // [1024,512] i32
    float* out = (float*)d_out;                 // [256,1024] f32

    float4* xT4 = (float4*)d_ws;                        // 1 MB
    float*  hT  = (float*)((char*)d_ws + (1 << 20));    // 0.5 MB (transposed h)

    // transpose x -> xT4 (64 blocks, ~2 MB traffic)
    pack_x<<<64, 256, 0, stream>>>(x, xT4);
    // layer 0: 1024 -> 512, min. 256 o-tiles x 2 bch = 512 blocks x 1024 thr
    //          -> 2 blocks/CU = 32 waves (100% occ). LDS 8K a + 16K red.
    daa_layer<1024, 16, true,  true ><<<512,  1024, 0, stream>>>(
        xT4, sel0, hT, 512);
    // layer 1: 512 -> 1024, max. 512 o-tiles x 2 bch = 1024 blocks x 1024 thr
    //          LDS 4K a + 16K red.
    daa_layer< 512, 16, false, false><<<1024, 1024, 0, stream>>>(
        (const float4*)hT, sel1, out, 1024);
}

// Round 9
// 26.261 us; speedup vs baseline: 1.3922x; 1.3922x over previous
//
#include <hip/hip_runtime.h>

// DAA autoencoder: two masked-reduction layers.
//   layer0: h[b][o]   = min_i ( sel0[o][i] ? x[b][i] : 2.0f )   (t-norm)
//   layer1: out[b][o] = max_i ( sel1[o][i] ? h[b][i] : -1.0f )  (t-conorm)
// B=256, IN=1024, HID=512.
//
// R8 lesson: OT 4->2 doubled vector x-loads (134->268 MB L2/layer) -> +9 us.
// The binding path is the vector x-load (count x L2 latency/BW), NOT the
// uniform addend fetch (R6 K$ == R7 LDS). R9: keep OT=4 (x-amortization as
// R7) and ADD V=2 batch-tiling: acc[4][2], per k-step 4 uniform ds_read +
// 2 vec loads + 48 VALU. Same vec-load count as R7, half the uniform
// fetches, 2x per-wave memory ILP.
//
// Bit-exactness: addend = sel ? 0.0f : +/-inf; x + 0 == x exactly; +/-inf
// never wins min/max vs finite; acc init = off (2.0/-1.0) reproduces the
// all-deselected row exactly.

#define NB 256   // batch

// ---- transpose x[256][1024] -> xT4[256][256] (float4 over i) -------------
__global__ __launch_bounds__(256) void pack_x(
    const float* __restrict__ in, float4* __restrict__ outT4)
{
    __shared__ float t[64][65];                 // [b][i] tile, +1 pad
    const int bx = blockIdx.x % 16;             // i-tile (1024/64)
    const int by = blockIdx.x / 16;             // b-tile (256/64)
    const int i0 = bx * 64, b0 = by * 64;

    const int li = threadIdx.x & 63;
    const int lb = threadIdx.x >> 6;
#pragma unroll
    for (int r = 0; r < 64; r += 4)
        t[lb + r][li] = in[(size_t)(b0 + lb + r) * 1024 + i0 + li];
    __syncthreads();

    const int sb = threadIdx.x & 63;
    const int si = threadIdx.x >> 6;
#pragma unroll
    for (int p = 0; p < 16; p += 4) {
        const int i4 = si + p;
        float4 v = make_float4(t[sb][4 * i4 + 0], t[sb][4 * i4 + 1],
                               t[sb][4 * i4 + 2], t[sb][4 * i4 + 3]);
        outT4[(size_t)(i0 / 4 + i4) * NB + b0 + sb] = v;
    }
}

// ---- masked min/max layer: OT=4 outputs x V=2 batches per lane -----------
template<int INF, int OT, int S, bool ISMIN, bool TOUT>
__global__ __launch_bounds__(64 * S, 8) void daa_layer(
    const float4* __restrict__ inT4,    // [INF/4][NB]
    const int* __restrict__ sel,        // [OUTF][INF] 0/1
    float* __restrict__ out, int OUTF)
{
    constexpr int C4  = INF / 4 / S;    // float4 k-steps per wave group
    constexpr int NI4 = OT * INF / 4;   // int4 count for the OT sel rows
    const int tid  = threadIdx.x;
    const int lane = tid & 63;
    const int s    = __builtin_amdgcn_readfirstlane(tid >> 6);
    const int bch  = blockIdx.x & 1;    // which 128-batch half
    const int o0   = (blockIdx.x >> 1) * OT;
    const int bA   = bch * 128 + lane;  // lane's first batch; second = bA+64
    const float off = ISMIN ? 2.0f : -1.0f;
    const float inf = ISMIN ? __builtin_inff() : -__builtin_inff();

    // ---- stage sel rows o0..o0+OT-1 expanded to float addends in LDS -----
    __shared__ float4 aLDS[NI4];
    if (tid < NI4) {
        const int4 v = ((const int4*)(sel + (size_t)o0 * INF))[tid];
        aLDS[tid] = make_float4(v.x ? 0.f : inf, v.y ? 0.f : inf,
                                v.z ? 0.f : inf, v.w ? 0.f : inf);
    }
    __syncthreads();

    float acc[OT][2];                   // [output row][batch chunk]
#pragma unroll
    for (int u = 0; u < OT; ++u) acc[u][0] = acc[u][1] = off;

    const float4* __restrict__ xp = inT4 + (size_t)(s * C4) * NB + bA;

#define MM(A, X, AV)                                                   \
    do {                                                               \
        if (ISMIN) {                                                   \
            A = fminf(fminf(A, (X).x + (AV).x), (X).y + (AV).y);       \
            A = fminf(fminf(A, (X).z + (AV).z), (X).w + (AV).w);       \
        } else {                                                       \
            A = fmaxf(fmaxf(A, (X).x + (AV).x), (X).y + (AV).y);       \
            A = fmaxf(fmaxf(A, (X).z + (AV).z), (X).w + (AV).w);       \
        }                                                              \
    } while (0)

    // 2-deep x prefetch (2 batches in flight per depth)
    float4 xa = xp[0], xb = xp[64];
    for (int c = 0; c < C4; ++c) {
        float4 na, nb;
        if (c + 1 < C4) {
            na = xp[(size_t)(c + 1) * NB];
            nb = xp[(size_t)(c + 1) * NB + 64];
        }
#pragma unroll
        for (int u = 0; u < OT; ++u) {
            // wave-uniform ds_read_b128 broadcast, amortized over 2 batches
            const float4 av = aLDS[u * (INF / 4) + s * C4 + c];
            MM(acc[u][0], xa, av);
            MM(acc[u][1], xb, av);
        }
        xa = na; xb = nb;
    }
#undef MM

    // ---- combine the S wave partials per (b,o) through LDS ---------------
    __shared__ float red[S][OT][2][64];     // [s][u][v][lane]
#pragma unroll
    for (int u = 0; u < OT; ++u)
#pragma unroll
        for (int v = 0; v < 2; ++v) red[s][u][v][lane] = acc[u][v];
    __syncthreads();

    if (tid < 128) {
        const int v  = tid >> 6;
        const int ln = tid & 63;
        const int b  = bch * 128 + v * 64 + ln;
        float r[OT];
#pragma unroll
        for (int u = 0; u < OT; ++u) {
            float q = red[0][u][v][ln];
#pragma unroll
            for (int ss = 1; ss < S; ++ss) {
                const float w = red[ss][u][v][ln];
                q = ISMIN ? fminf(q, w) : fmaxf(q, w);
            }
            r[u] = q;
        }
        static_assert(OT == 4, "float4 store assumes OT==4");
        const float4 o4 = make_float4(r[0], r[1], r[2], r[3]);
        if (TOUT)   // transposed: float4 row (o0>>2), col b  (o0 % 4 == 0)
            ((float4*)out)[(size_t)(o0 >> 2) * NB + b] = o4;
        else        // out[b][o0..o0+3] contiguous
            *(float4*)(out + (size_t)b * OUTF + o0) = o4;
    }
}

extern "C" void kernel_launch(void* const* d_in, const int* in_sizes, int n_in,
                              void* d_out, int out_size, void* d_ws, size_t ws_size,
                              hipStream_t stream) {
    const float* x    = (const float*)d_in[0];  // [256,1024] f32
    const int*   sel0 = (const int*)d_in[1];    // [512,1024] i32
    const int*   sel1 = (const int*)d_in[2];    // [1024,512] i32
    float* out = (float*)d_out;                 // [256,1024] f32

    float4* xT4 = (float4*)d_ws;                        // 1 MB
    float*  hT  = (float*)((char*)d_ws + (1 << 20));    // 0.5 MB (transposed h)

    // transpose x -> xT4 (64 blocks, ~2 MB traffic)
    pack_x<<<64, 256, 0, stream>>>(x, xT4);
    // layer 0: 1024 -> 512, min. 128 o-tiles x 2 bch = 256 blocks x 1024 thr
    //          (16 waves/CU; 64 x-loads in flight/CU). LDS 16K a + 32K red.
    daa_layer<1024, 4, 16, true,  true ><<<256, 1024, 0, stream>>>(
        xT4, sel0, hT, 512);
    // layer 1: 512 -> 1024, max. 256 o-tiles x 2 bch = 512 blocks x 1024 thr
    //          (2 blocks/CU = 32 waves, 100% occ). LDS 8K a + 32K red.
    daa_layer< 512, 4, 16, false, false><<<512, 1024, 0, stream>>>(
        (const float4*)hT, sel1, out, 1024);
}

// Round 10
// 25.348 us; speedup vs baseline: 1.4424x; 1.0360x over previous
//
#include <hip/hip_runtime.h>

// DAA autoencoder: two masked-reduction layers.
//   layer0: h[b][o]   = min_i ( sel0[o][i] ? x[b][i] : 2.0f )   (t-norm)
//   layer1: out[b][o] = max_i ( sel1[o][i] ? h[b][i] : -1.0f )  (t-conorm)
// B=256, IN=1024, HID=512.
//
// R8/R9 A/B isolated the binding resource: per-CU vector-memory throughput,
// ~20-24 cy per 1KB wave-load. R10: halve vec-loads per edge via OT=8
// (64 MB x-restream per layer), V=1, bch=4 to keep 256+ blocks. The now-8
// uniform addend fetches per k-step are split across two pipes: rows 0-3
// via LDS broadcast, rows 4-7 via s_load from a pre-expanded global array
// (each pipe at the 4/k-step level R6/R7 proved fine). Reduction LDS unions
// with addend LDS (32 KB total, barrier-separated).
//
// Bit-exactness: addend = sel ? 0.0f : +/-inf; x + 0.0f == x exactly (x
// never -0); +/-inf never wins min/max vs finite; acc init = off (2.0/-1.0)
// reproduces the all-deselected row exactly.

#define NB 256   // batch

// ---- pack: transpose x AND expand the scalar-path half of sel ------------
// a0h rows j=(ot*4+r): sel0 row ot*8+4+r, r=0..3.  a1h likewise for sel1.
__global__ __launch_bounds__(256) void pack_all(
    const float* __restrict__ x,    float4* __restrict__ xT4,   // [256][256]
    const int*   __restrict__ sel0, float4* __restrict__ a0h,   // [256][256]
    const int*   __restrict__ sel1, float4* __restrict__ a1h)   // [512][128]
{
    const int t = blockIdx.x * 256 + threadIdx.x;   // 65536 threads
    const float pinf = __builtin_inff();

    {   // a0h: 65536 float4 (1 MB), +inf fill
        const int j = t >> 8, i4 = t & 255;
        const int srow = (j >> 2) * 8 + 4 + (j & 3);
        const int4 v = ((const int4*)sel0)[srow * 256 + i4];
        a0h[t] = make_float4(v.x ? 0.f : pinf, v.y ? 0.f : pinf,
                             v.z ? 0.f : pinf, v.w ? 0.f : pinf);
    }
    {   // a1h: 65536 float4 (1 MB), -inf fill
        const int j = t >> 7, i4 = t & 127;
        const int srow = (j >> 2) * 8 + 4 + (j & 3);
        const int4 v = ((const int4*)sel1)[srow * 128 + i4];
        a1h[t] = make_float4(v.x ? 0.f : -pinf, v.y ? 0.f : -pinf,
                             v.z ? 0.f : -pinf, v.w ? 0.f : -pinf);
    }

    // ---- x transpose: blocks 0..63 only ----
    if (blockIdx.x < 64) {
        __shared__ float tt[64][65];
        const int bx = blockIdx.x % 16;             // i-tile
        const int by = blockIdx.x / 16;             // b-tile
        const int i0 = bx * 64, b0 = by * 64;

        const int li = threadIdx.x & 63;
        const int lb = threadIdx.x >> 6;
#pragma unroll
        for (int r = 0; r < 64; r += 4)
            tt[lb + r][li] = x[(size_t)(b0 + lb + r) * 1024 + i0 + li];
        __syncthreads();

        const int sb = threadIdx.x & 63;
        const int si = threadIdx.x >> 6;
#pragma unroll
        for (int p = 0; p < 16; p += 4) {
            const int i4 = si + p;
            float4 v = make_float4(tt[sb][4 * i4 + 0], tt[sb][4 * i4 + 1],
                                   tt[sb][4 * i4 + 2], tt[sb][4 * i4 + 3]);
            xT4[(size_t)(i0 / 4 + i4) * NB + b0 + sb] = v;
        }
    }
}

// ---- masked min/max layer: OT=8 outputs per block, 64 batches ------------
template<int INF, int S, int MW, bool ISMIN, bool TOUT>
__global__ __launch_bounds__(64 * S, MW) void daa_layer(
    const float4* __restrict__ inT4,   // [INF/4][NB]
    const int*    __restrict__ sel,    // [OUTF][INF] (rows o0..o0+3 -> LDS)
    const float4* __restrict__ agh,    // pre-expanded rows (o&7)>=4, [.][INF/4]
    float* __restrict__ out, int OUTF)
{
    constexpr int C4  = INF / 4 / S;   // float4 k-steps per wave
    constexpr int R4  = INF / 4;       // float4s per addend row
    const int tid  = threadIdx.x;
    const int lane = tid & 63;
    const int s    = __builtin_amdgcn_readfirstlane(tid >> 6);
    const int bch  = blockIdx.x & 3;   // 64-batch chunk
    const int o0   = (blockIdx.x >> 2) * 8;
    const int b    = bch * 64 + lane;
    const float off = ISMIN ? 2.0f : -1.0f;
    const float inf = ISMIN ? __builtin_inff() : -__builtin_inff();

    // 32 KB LDS, time-shared: [0, 4*R4) float4 = addend rows 0..3 during the
    // k-loop; reused as float red[16][8][64] afterwards (barrier-separated).
    __shared__ float4 uni[2048];

    // stage addend rows o0..o0+3 (expand int4 -> float4)
    if (tid < 4 * R4) {
        const int4 v = ((const int4*)sel)[(size_t)o0 * R4 + tid];
        uni[tid] = make_float4(v.x ? 0.f : inf, v.y ? 0.f : inf,
                               v.z ? 0.f : inf, v.w ? 0.f : inf);
    }
    __syncthreads();

    float acc[8];
#pragma unroll
    for (int u = 0; u < 8; ++u) acc[u] = off;

    const float4* __restrict__ xp = inT4 + (size_t)(s * C4) * NB + b;
    const float4* __restrict__ aL = uni + s * C4;                       // LDS
    const float4* __restrict__ aG = agh + ((size_t)(o0 >> 3) * 4) * R4 + s * C4;

#define MM(A, X, AV)                                                   \
    do {                                                               \
        if (ISMIN) {                                                   \
            A = fminf(fminf(A, (X).x + (AV).x), (X).y + (AV).y);       \
            A = fminf(fminf(A, (X).z + (AV).z), (X).w + (AV).w);       \
        } else {                                                       \
            A = fmaxf(fmaxf(A, (X).x + (AV).x), (X).y + (AV).y);       \
            A = fmaxf(fmaxf(A, (X).z + (AV).z), (X).w + (AV).w);       \
        }                                                              \
    } while (0)

    float4 xa = xp[0];
    for (int c = 0; c < C4; ++c) {
        float4 nx = xa;
        if (c + 1 < C4) nx = xp[(size_t)(c + 1) * NB];
#pragma unroll
        for (int u = 0; u < 4; ++u) {       // LDS broadcast path
            const float4 av = aL[u * R4 + c];
            MM(acc[u], xa, av);
        }
#pragma unroll
        for (int u = 0; u < 4; ++u) {       // scalar s_load path
            const float4 av = aG[u * R4 + c];
            MM(acc[4 + u], xa, av);
        }
        xa = nx;
    }
#undef MM

    __syncthreads();                    // all addend-LDS reads complete
    float* redf = (float*)uni;          // red[s][u][lane] = 16*8*64 floats
#pragma unroll
    for (int u = 0; u < 8; ++u) redf[(s * 8 + u) * 64 + lane] = acc[u];
    __syncthreads();

    if (tid < 512) {                    // merge 16 partials per (u, lane)
        const int u = tid >> 6, ln = tid & 63;
        float v = redf[u * 64 + ln];
#pragma unroll
        for (int ss = 1; ss < S; ++ss) {
            const float q = redf[(ss * 8 + u) * 64 + ln];
            v = ISMIN ? fminf(v, q) : fmaxf(v, q);
        }
        redf[u * 64 + ln] = v;          // slot [0][u][ln]: owner-only, race-free
    }
    __syncthreads();

    if (tid < 64) {                     // coalesced float4 stores
        const int bb = bch * 64 + tid;
        const float4 lo = make_float4(redf[0 * 64 + tid], redf[1 * 64 + tid],
                                      redf[2 * 64 + tid], redf[3 * 64 + tid]);
        const float4 hi = make_float4(redf[4 * 64 + tid], redf[5 * 64 + tid],
                                      redf[6 * 64 + tid], redf[7 * 64 + tid]);
        if (TOUT) {                     // transposed: rows o0>>2, o0>>2 + 1
            ((float4*)out)[(size_t)(o0 >> 2) * NB + bb]       = lo;
            ((float4*)out)[((size_t)(o0 >> 2) + 1) * NB + bb] = hi;
        } else {                        // out[bb][o0..o0+7]
            float4* p = (float4*)(out + (size_t)bb * OUTF + o0);
            p[0] = lo; p[1] = hi;
        }
    }
}

extern "C" void kernel_launch(void* const* d_in, const int* in_sizes, int n_in,
                              void* d_out, int out_size, void* d_ws, size_t ws_size,
                              hipStream_t stream) {
    const float* x    = (const float*)d_in[0];  // [256,1024] f32
    const int*   sel0 = (const int*)d_in[1];    // [512,1024] i32
    const int*   sel1 = (const int*)d_in[2];    // [1024,512] i32
    float* out = (float*)d_out;                 // [256,1024] f32

    char* ws = (char*)d_ws;
    float4* xT4 = (float4*)ws;                          // 1 MB
    float*  hT  = (float*)(ws + (1 << 20));             // 0.5 MB (transposed h)
    float4* a0h = (float4*)(ws + 3 * (1 << 19));        // 1 MB @1.5MB
    float4* a1h = (float4*)(ws + 5 * (1 << 19));        // 1 MB @2.5MB

    // transpose x + expand scalar-path sel halves (256 blocks)
    pack_all<<<256, 256, 0, stream>>>(x, xT4, sel0, a0h, sel1, a1h);
    // layer 0: 1024 -> 512, min. 64 o-tiles x 4 bch = 256 blocks x 1024 thr
    //          (16 waves/CU). MW=4: 1 block/CU regardless, allow 128 VGPR.
    daa_layer<1024, 16, 4, true,  true ><<<256, 1024, 0, stream>>>(
        xT4, sel0, a0h, hT, 512);
    // layer 1: 512 -> 1024, max. 128 o-tiles x 4 bch = 512 blocks x 1024 thr
    //          MW=8 caps VGPR at 64 -> 2 blocks/CU (100% occ).
    daa_layer< 512, 16, 8, false, false><<<512, 1024, 0, stream>>>(
        (const float4*)hT, sel1, a1h, out, 1024);
}